// Round 13
// baseline (239.858 us; speedup 1.0000x reference)
//
#include <hip/hip_runtime.h>
#include <cstdint>

typedef __attribute__((ext_vector_type(8))) short bf16x8;
typedef __attribute__((ext_vector_type(16))) float f32x16;
typedef unsigned long long ull;

#define BN_NB 256
#define LRELU_SLOPE 0.1f
#define GTILE 128   // P-rows per pair-GEMM tile

__device__ __forceinline__ float bf2f(ushort h) {
    union { uint u; float v; } x; x.u = ((uint)h) << 16; return x.v;
}
__device__ __forceinline__ ushort f2bf(float f) {
    union { float v; uint u; } x; x.v = f;
    const uint r = (x.u + 0x7FFFu + ((x.u >> 16) & 1u)) >> 16;  // RNE
    return (ushort)r;
}

// async 16B global->LDS (wave-uniform LDS base + lane*16)
__device__ __forceinline__ void gload_lds16(const void* g, void* l) {
    __builtin_amdgcn_global_load_lds((const __attribute__((address_space(1))) void*)g,
                                     (__attribute__((address_space(3))) void*)l, 16, 0, 0);
}

// ---------------------------------------------------------------------------
// Zero sentinel feature rows.
// ---------------------------------------------------------------------------
__global__ __launch_bounds__(128) void zero_rows(ushort* __restrict__ xbz,
                                                 ushort* __restrict__ f1z,
                                                 ushort* __restrict__ f2z)
{
    const int t = threadIdx.x;
    if (t < 96) xbz[t] = 0;
    if (t < 64) { f1z[t] = 0; f2z[t] = 0; }
}

// ---------------------------------------------------------------------------
// x (fp32) -> bf16, vectorized
// ---------------------------------------------------------------------------
__global__ __launch_bounds__(256) void cvt_bf16(const float* __restrict__ in,
                                                ushort* __restrict__ out, int n4)
{
    for (int i = blockIdx.x * 256 + threadIdx.x; i < n4; i += gridDim.x * 256) {
        const float4 v = reinterpret_cast<const float4*>(in)[i];
        ushort4 o;
        o.x = f2bf(v.x); o.y = f2bf(v.y); o.z = f2bf(v.z); o.w = f2bf(v.w);
        reinterpret_cast<ushort4*>(out)[i] = o;
    }
}

// ---------------------------------------------------------------------------
// Pack W[K][CIN][64] fp32 -> bf16 B-fragments for mfma_f32_32x32x16_bf16.
// Chunk c = ks*2 + ct; lane l holds W[tap][ks*16+(l>>5)*8+e][ct*32+(l&31)].
// ---------------------------------------------------------------------------
template<int K, int CIN>
__global__ __launch_bounds__(256) void pack_W(const float* __restrict__ W,
                                              ushort* __restrict__ Bp)
{
    constexpr int KS = CIN / 16;
    constexpr int CHUNKS = KS * 2;
    const int t = blockIdx.x * 256 + threadIdx.x;
    if (t >= K * CHUNKS * 64) return;
    const int l = t & 63;
    const int s = t >> 6;
    const int c = s % CHUNKS;
    const int tap = s / CHUNKS;
    const int ks = c >> 1;
    const int ct = c & 1;
    const int k0 = ks * 16 + (l >> 5) * 8;
    const int col = ct * 32 + (l & 31);
    bf16x8 v;
#pragma unroll
    for (int e = 0; e < 8; ++e)
        v[e] = (short)f2bf(W[((size_t)tap * CIN + k0 + e) * 64 + col]);
    *reinterpret_cast<bf16x8*>(Bp + (size_t)t * 8) = v;
}

// ---------------------------------------------------------------------------
// pk1: per-(tap, block) valid counts + per-wave validity ballots (NO atomics).
// cnt2d[k*nblk + blk] = block count; mask2d[(k*nblk+blk)*4 + w] = wave ballot.
// ---------------------------------------------------------------------------
template<int K>
__global__ __launch_bounds__(256) void pk1_count(const int* __restrict__ nmap,
                                                 int nout, int nin, int nblk,
                                                 int* __restrict__ cnt2d,
                                                 ull* __restrict__ mask2d)
{
    __shared__ int wc[32][4];
    const int t = threadIdx.x;
    const int l = t & 63;
    const int w = t >> 6;
    const int rr = blockIdx.x * 256 + w * 64 + l;
    const bool inb = rr < nout;
    const int* bp = nmap + (size_t)(inb ? rr : 0) * K;   // safe base for tail
#pragma unroll
    for (int k = 0; k < K; ++k) {
        const int idx = bp[k];
        const ull m = __ballot(inb && idx < nin);
        if (l == 0) {
            wc[k][w] = __popcll(m);
            mask2d[((size_t)k * nblk + blockIdx.x) * 4 + w] = m;
        }
    }
    __syncthreads();
    if (t < K)
        cnt2d[(size_t)t * nblk + blockIdx.x] = wc[t][0] + wc[t][1] + wc[t][2] + wc[t][3];
}

// ---------------------------------------------------------------------------
// pk2: one-block exclusive scan over flattened cnt2d[K*nblk] -> base2d;
// meta[0..K] = tap starts, meta[64] = ntiles; tilemap filled.
// ---------------------------------------------------------------------------
template<int K>
__global__ __launch_bounds__(256) void pk2_scan(const int* __restrict__ cnt2d, int nblk,
                                                int* __restrict__ base2d,
                                                int* __restrict__ meta,
                                                int* __restrict__ tilemap)
{
    __shared__ int buf[6600];
    __shared__ int psum[256];
    __shared__ int tofh[32];
    const int t = threadIdx.x;
    const int n = K * nblk;
    const int chunk = (n + 255) / 256;
    const int lo = t * chunk;
    const int hi = min(n, lo + chunk);

    int s = 0;
    for (int i = lo; i < hi; ++i) { const int v = cnt2d[i]; buf[i] = v; s += v; }
    psum[t] = s;
    __syncthreads();
    for (int off = 1; off < 256; off <<= 1) {
        const int mine = psum[t];
        const int add = (t >= off) ? psum[t - off] : 0;
        __syncthreads();
        psum[t] = mine + add;
        __syncthreads();
    }
    int run = (t > 0) ? psum[t - 1] : 0;
    for (int i = lo; i < hi; ++i) { base2d[i] = run; run += buf[i]; }
    __syncthreads();
    if (t < K) meta[t] = base2d[(size_t)t * nblk];
    if (t == 0) meta[K] = psum[255];
    __syncthreads();
    if (t == 0) {
        int nt = 0;
        for (int k = 0; k < K; ++k) {
            tofh[k] = nt;
            const int c = ((k + 1 < K) ? meta[k + 1] : meta[K]) - meta[k];
            nt += (c + GTILE - 1) / GTILE;
        }
        tofh[K] = nt;
        meta[64] = nt;
    }
    __syncthreads();
    for (int k = 0; k < K; ++k) {
        const int tiles = tofh[k + 1] - tofh[k];
        for (int j = t; j < tiles; j += 256)
            tilemap[tofh[k] + j] = (k << 16) | j;
    }
}

// ---------------------------------------------------------------------------
// pk3: deterministic slot assignment from precomputed ballots (NO atomics,
// NO arrays, nothing live across a barrier -> no scratch).
// slot = base2d[k][blk] + popcll(masks of waves below) + popcll(mask & below).
// ---------------------------------------------------------------------------
template<int K>
__global__ __launch_bounds__(256) void pk3_fill(const int* __restrict__ nmap,
                                                int nout, int nin, int nblk,
                                                const int* __restrict__ base2d,
                                                const ull* __restrict__ mask2d,
                                                int* __restrict__ pos,
                                                int* __restrict__ IL)
{
    const int t = threadIdx.x;
    const int l = t & 63;
    const int w = t >> 6;
    const int rr = blockIdx.x * 256 + w * 64 + l;
    const bool inb = rr < nout;
    const int* bp = nmap + (size_t)(inb ? rr : 0) * K;
    const ull below = (l == 63) ? 0x7FFFFFFFFFFFFFFFULL : ((1ULL << l) - 1ULL);

#pragma unroll
    for (int k = 0; k < K; ++k) {
        const ull* mp = mask2d + ((size_t)k * nblk + blockIdx.x) * 4;
        const ull m0 = mp[0], m1 = mp[1], m2 = mp[2], m3 = mp[3];
        const ull mw = (w == 0) ? m0 : (w == 1) ? m1 : (w == 2) ? m2 : m3;
        int woff = 0;
        if (w > 0) woff += __popcll(m0);
        if (w > 1) woff += __popcll(m1);
        if (w > 2) woff += __popcll(m2);
        const bool v = (mw >> l) & 1ULL;
        const int slot = base2d[(size_t)k * nblk + blockIdx.x] + woff + __popcll(mw & below);
        if (inb) pos[(size_t)k * nout + rr] = v ? slot : -1;
        if (v) IL[slot] = bp[k];
    }
}

// ---------------------------------------------------------------------------
// pair-GEMM: per tile (tap k, 128 valid pairs) one dense MFMA pass.
// Block: 256 thr = 4 waves x 32 P-rows; B slice staged once per tile into
// LDS via global_load_lds; A gathered per-lane (valid pairs only).
// P[slot][64] bf16 written coalesced. Tail rows use the zero feature row.
// ---------------------------------------------------------------------------
template<int K, int CIN>
__global__ __launch_bounds__(256) void pair_gemm(
    const ushort* __restrict__ fin, int nin,
    const int* __restrict__ IL,
    const int* __restrict__ meta,     // ts at [0..K], ntiles at [64]
    const int* __restrict__ tilemap,
    const ushort* __restrict__ Bp,
    ushort* __restrict__ P)
{
    constexpr int KS = CIN / 16;
    constexpr int CH = KS * 2;
    constexpr int CPW = CH / 4;
    __shared__ ushort Bb[CH * 512];

    const int tid = threadIdx.x;
    const int l = tid & 63;
    const int w = tid >> 6;
    const int lrow = l & 31;
    const int hi = l >> 5;
    const int ntiles = meta[64];

    for (int t = blockIdx.x; t < ntiles; t += gridDim.x) {
        const int info = tilemap[t];
        const int k = info >> 16;
        const int j = info & 0xFFFF;
        const int tsk = meta[k];
        const int cntk = ((k + 1 < K) ? meta[k + 1] : meta[K]) - tsk;
        const int rbase = j * GTILE;

#pragma unroll
        for (int c = 0; c < CPW; ++c) {
            const int cc = w * CPW + c;
            gload_lds16(Bp + ((size_t)k * CH + cc) * 512 + l * 8, &Bb[cc * 512]);
        }

        const int rin = rbase + w * 32 + lrow;
        const int idx = (rin < cntk) ? IL[tsk + rin] : nin;  // tail -> zero row
        const ushort* rp = fin + (size_t)idx * CIN + hi * 8;
        __syncthreads();   // B staged & visible

        bf16x8 a[KS];
#pragma unroll
        for (int ks = 0; ks < KS; ++ks)
            a[ks] = *reinterpret_cast<const bf16x8*>(rp + ks * 16);

        f32x16 acc0, acc1;
#pragma unroll
        for (int q = 0; q < 16; ++q) { acc0[q] = 0.f; acc1[q] = 0.f; }
#pragma unroll
        for (int ks = 0; ks < KS; ++ks) {
            const bf16x8 b0 = *reinterpret_cast<const bf16x8*>(&Bb[(ks * 2 + 0) * 512 + l * 8]);
            acc0 = __builtin_amdgcn_mfma_f32_32x32x16_bf16(a[ks], b0, acc0, 0, 0, 0);
            const bf16x8 b1 = *reinterpret_cast<const bf16x8*>(&Bb[(ks * 2 + 1) * 512 + l * 8]);
            acc1 = __builtin_amdgcn_mfma_f32_32x32x16_bf16(a[ks], b1, acc1, 0, 0, 0);
        }

        const int prow0 = tsk + rbase + w * 32;
#pragma unroll
        for (int reg = 0; reg < 16; ++reg) {
            const int rowD = (reg & 3) + 8 * (reg >> 2) + 4 * hi;
            if (rbase + w * 32 + rowD < cntk) {
                ushort* pp = P + (size_t)(prow0 + rowD) * 64 + lrow;
                pp[0]  = f2bf(acc0[reg]);
                pp[32] = f2bf(acc1[reg]);
            }
        }
        __syncthreads();   // reads done before next tile's stage
    }
}

// ---------------------------------------------------------------------------
// pair-reduce: out[r] = act( sum_{k valid} P[pos[k][r]] + bias ).
// Block = 64 rows x 4 col-groups; acc[16]/thread (register-light).
// ---------------------------------------------------------------------------
template<int K, bool LEAKY, bool OUTF32>
__global__ __launch_bounds__(256) void pair_reduce(
    const int* __restrict__ pos, int nout,
    const ushort* __restrict__ P,
    const float* __restrict__ bias,
    void* __restrict__ fout)
{
    const int t = threadIdx.x;
    const int r = blockIdx.x * 64 + (t & 63);
    const int cg = t >> 6;           // 0..3 -> channels cg*16..+15
    if (r >= nout) return;
    float acc[16];
#pragma unroll
    for (int c = 0; c < 16; ++c) acc[c] = 0.f;
#pragma unroll
    for (int k = 0; k < K; ++k) {
        const int p = pos[(size_t)k * nout + r];
        if (p >= 0) {
            const ushort* pr = P + (size_t)p * 64 + cg * 16;
            const bf16x8 v0 = *reinterpret_cast<const bf16x8*>(pr);
            const bf16x8 v1 = *reinterpret_cast<const bf16x8*>(pr + 8);
#pragma unroll
            for (int e = 0; e < 8; ++e) {
                acc[e]     += bf2f((ushort)v0[e]);
                acc[8 + e] += bf2f((ushort)v1[e]);
            }
        }
    }
    if (OUTF32) {
        float* o = reinterpret_cast<float*>(fout) + (size_t)r * 64 + cg * 16;
#pragma unroll
        for (int c = 0; c < 16; ++c) {
            float v = acc[c] + bias[cg * 16 + c];
            if (LEAKY) v = v >= 0.f ? v : LRELU_SLOPE * v;
            o[c] = v;
        }
    } else {
        ushort* o = reinterpret_cast<ushort*>(fout) + (size_t)r * 64 + cg * 16;
#pragma unroll
        for (int c = 0; c < 16; ++c) {
            float v = acc[c] + bias[cg * 16 + c];
            if (LEAKY) v = v >= 0.f ? v : LRELU_SLOPE * v;
            o[c] = f2bf(v);
        }
    }
}

// ---------------------------------------------------------------------------
// BatchNorm stage 1 (bf16 input): deterministic per-block partial sum/sumsq.
// ---------------------------------------------------------------------------
__global__ __launch_bounds__(256) void bn_partial(const ushort* __restrict__ f2v, int n2,
                                                  float* __restrict__ partials)
{
    const int c = threadIdx.x & 63;
    const int g = threadIdx.x >> 6;
    float s = 0.f, ss = 0.f;
    for (int r = blockIdx.x * 4 + g; r < n2; r += gridDim.x * 4) {
        const float v = bf2f(f2v[(size_t)r * 64 + c]);
        s += v;
        ss = fmaf(v, v, ss);
    }
    __shared__ float red[4][128];
    red[g][c] = s;
    red[g][64 + c] = ss;
    __syncthreads();
    if (g == 0) {
        partials[(size_t)blockIdx.x * 128 + c] =
            red[0][c] + red[1][c] + red[2][c] + red[3][c];
        partials[(size_t)blockIdx.x * 128 + 64 + c] =
            red[0][64 + c] + red[1][64 + c] + red[2][64 + c] + red[3][64 + c];
    }
}

// ---------------------------------------------------------------------------
// BatchNorm stage 2: PARALLEL final reduce -> per-channel affine (scale folded)
// ---------------------------------------------------------------------------
__global__ __launch_bounds__(1024) void bn_finalize(const float* __restrict__ partials, int n2,
                                                    const float* __restrict__ gamma,
                                                    const float* __restrict__ beta,
                                                    const float* __restrict__ scale,
                                                    float* __restrict__ affA, float* __restrict__ affB)
{
    const int t = threadIdx.x;
    const int col = t & 127;
    const int g = t >> 7;
    float s = 0.f;
#pragma unroll
    for (int b = g; b < BN_NB; b += 8)
        s += partials[(size_t)b * 128 + col];
    __shared__ float red[8][128];
    red[g][col] = s;
    __syncthreads();
    if (g == 0) {
        float S = red[0][col];
#pragma unroll
        for (int i = 1; i < 8; ++i) S += red[i][col];
        red[0][col] = S;
    }
    __syncthreads();
    if (t < 64) {
        const float S = red[0][t];
        const float SS = red[0][64 + t];
        const float inv_n = 1.f / (float)n2;
        const float mu = S * inv_n;
        const float var = fmaxf(SS * inv_n - mu * mu, 0.f);
        const float rs = rsqrtf(var + 1e-5f);
        const float sc = scale[0];
        const float ga = gamma[t];
        affA[t] = rs * ga * sc;
        affB[t] = (beta[t] - mu * rs * ga) * sc;
    }
}

// ---------------------------------------------------------------------------
// In-place BN affine on f2 (bf16): f2 = f2*a + b.
// ---------------------------------------------------------------------------
__global__ __launch_bounds__(256) void aff_apply(ushort* __restrict__ f2, int nchunk,
                                                 const float* __restrict__ affA,
                                                 const float* __restrict__ affB)
{
    for (int i = blockIdx.x * 256 + threadIdx.x; i < nchunk; i += gridDim.x * 256) {
        const int c = i & 7;
        bf16x8 v = *reinterpret_cast<const bf16x8*>(f2 + (size_t)i * 8);
#pragma unroll
        for (int j = 0; j < 8; ++j)
            v[j] = (short)f2bf(fmaf(bf2f((ushort)v[j]), affA[c * 8 + j], affB[c * 8 + j]));
        *reinterpret_cast<bf16x8*>(f2 + (size_t)i * 8) = v;
    }
}

extern "C" void kernel_launch(void* const* d_in, const int* in_sizes, int n_in,
                              void* d_out, int out_size, void* d_ws, size_t ws_size,
                              hipStream_t stream)
{
    const float* x     = (const float*)d_in[0];
    const float* W1    = (const float*)d_in[1];
    const float* b1    = (const float*)d_in[2];
    const float* W2    = (const float*)d_in[3];
    const float* b2    = (const float*)d_in[4];
    const float* W3    = (const float*)d_in[5];
    const float* b3    = (const float*)d_in[6];
    const float* gamma = (const float*)d_in[7];
    const float* beta  = (const float*)d_in[8];
    const float* scale = (const float*)d_in[9];
    const int* nmap1   = (const int*)d_in[10];
    const int* nmap2   = (const int*)d_in[11];
    const int* nmap3   = (const int*)d_in[12];

    const int N  = in_sizes[0] / 96;    // stride-1 points
    const int N2 = in_sizes[11] / 8;    // stride-2 points
    const int E1 = 27 * N;              // max pairs (sizes pos/IL/P)

    // ---- workspace layout (every region 16B-aligned) ----
    ushort* xb  = (ushort*)d_ws;                    // [N+1,96] bf16
    ushort* f1  = xb + (size_t)(N + 1) * 96;        // [N+1,64] bf16
    ushort* f2  = f1 + (size_t)(N + 1) * 64;        // [N2+1,64] bf16
    ushort* Bp1 = f2 + (size_t)(N2 + 1) * 64;       // 27*96*64
    ushort* Bp2 = Bp1 + 27 * 96 * 64;               // 8*64*64
    ushort* Bp3 = Bp2 + 8 * 64 * 64;                // 27*64*64
    float* partials = (float*)(Bp3 + 27 * 64 * 64); // [BN_NB,128] f32
    float* affA = partials + (size_t)BN_NB * 128;   // [64]
    float* affB = affA + 64;                        // [64]
    int* meta   = (int*)(affB + 64);                // 128 ints
    int* tmap   = meta + 128;                       // 16384 ints
    int* cnt2d  = tmap + 16384;                     // 8192 ints
    int* base2d = cnt2d + 8192;                     // 8192 ints
    ull* mask2d = (ull*)(base2d + 8192);            // 27*256*4 ull (221 KB)
    int* pos    = (int*)(mask2d + 27 * 256 * 4);    // E1 ints
    int* IL     = pos + E1;                         // E1 ints
    ushort* P   = (ushort*)(IL + E1);               // [E1, 64] bf16
    float* out  = (float*)d_out;                    // [N2,64] fp32

    const int gN  = (N + 255) / 256;
    const int gN2 = (N2 + 255) / 256;

    // ---- prologue ----
    zero_rows<<<1, 128, 0, stream>>>(xb + (size_t)N * 96, f1 + (size_t)N * 64,
                                     f2 + (size_t)N2 * 64);
    cvt_bf16<<<2048, 256, 0, stream>>>(x, xb, N * 96 / 4);
    pack_W<27, 96><<<(27 * 12 * 64 + 255) / 256, 256, 0, stream>>>(W1, Bp1);
    pack_W<8, 64><<<(8 * 8 * 64 + 255) / 256, 256, 0, stream>>>(W2, Bp2);
    pack_W<27, 64><<<(27 * 8 * 64 + 255) / 256, 256, 0, stream>>>(W3, Bp3);

    // ---- conv1: k=27, 96->64, leaky ----
    pk1_count<27><<<gN, 256, 0, stream>>>(nmap1, N, N, gN, cnt2d, mask2d);
    pk2_scan<27><<<1, 256, 0, stream>>>(cnt2d, gN, base2d, meta, tmap);
    pk3_fill<27><<<gN, 256, 0, stream>>>(nmap1, N, N, gN, base2d, mask2d, pos, IL);
    pair_gemm<27, 96><<<2048, 256, 0, stream>>>(xb, N, IL, meta, tmap, Bp1, P);
    pair_reduce<27, true, false><<<(N + 63) / 64, 256, 0, stream>>>(pos, N, P, b1, f1);

    // ---- conv2: k=8, 64->64, leaky (downsample) ----
    pk1_count<8><<<gN2, 256, 0, stream>>>(nmap2, N2, N, gN2, cnt2d, mask2d);
    pk2_scan<8><<<1, 256, 0, stream>>>(cnt2d, gN2, base2d, meta, tmap);
    pk3_fill<8><<<gN2, 256, 0, stream>>>(nmap2, N2, N, gN2, base2d, mask2d, pos, IL);
    pair_gemm<8, 64><<<2048, 256, 0, stream>>>(f1, N, IL, meta, tmap, Bp2, P);
    pair_reduce<8, true, false><<<(N2 + 63) / 64, 256, 0, stream>>>(pos, N2, P, b2, f2);

    // ---- batchnorm (deterministic two-stage) + in-place affine ----
    bn_partial<<<BN_NB, 256, 0, stream>>>(f2, N2, partials);
    bn_finalize<<<1, 1024, 0, stream>>>(partials, N2, gamma, beta, scale, affA, affB);
    aff_apply<<<2048, 256, 0, stream>>>(f2, N2 * 8, affA, affB);

    // ---- conv3: k=27, 64->64, fp32 out ----
    pk1_count<27><<<gN2, 256, 0, stream>>>(nmap3, N2, N2, gN2, cnt2d, mask2d);
    pk2_scan<27><<<1, 256, 0, stream>>>(cnt2d, gN2, base2d, meta, tmap);
    pk3_fill<27><<<gN2, 256, 0, stream>>>(nmap3, N2, N2, gN2, base2d, mask2d, pos, IL);
    pair_gemm<27, 64><<<2048, 256, 0, stream>>>(f2, N2, IL, meta, tmap, Bp3, P);
    pair_reduce<27, false, true><<<(N2 + 63) / 64, 256, 0, stream>>>(pos, N2, P, b3, out);
}

// Round 14
// 138.086 us; speedup vs baseline: 1.7370x; 1.7370x over previous
//
#include <hip/hip_runtime.h>
#include <cstdint>

typedef __attribute__((ext_vector_type(8))) short bf16x8;
typedef __attribute__((ext_vector_type(4))) float f32x4;

#define BN_NB 256
#define LRELU_SLOPE 0.1f

__device__ __forceinline__ float bf2f(ushort h) {
    union { uint u; float v; } x; x.u = ((uint)h) << 16; return x.v;
}
__device__ __forceinline__ ushort f2bf(float f) {
    union { float v; uint u; } x; x.v = f;
    const uint r = (x.u + 0x7FFFu + ((x.u >> 16) & 1u)) >> 16;  // RNE
    return (ushort)r;
}

// m204 bijective XCD swizzle: contiguous grid chunk per XCD (8 XCDs).
__device__ __forceinline__ int xcd_swizzle(int bid, int nwg) {
    const int q = nwg >> 3, r = nwg & 7;
    const int xcd = bid & 7, local = bid >> 3;
    return (xcd < r ? xcd * (q + 1) : r * (q + 1) + (xcd - r) * q) + local;
}

// async 16B global->LDS (wave-uniform LDS base + lane*16)
__device__ __forceinline__ void gload_lds16(const void* g, void* l) {
    __builtin_amdgcn_global_load_lds((const __attribute__((address_space(1))) void*)g,
                                     (__attribute__((address_space(3))) void*)l, 16, 0, 0);
}

// ---------------------------------------------------------------------------
// x (fp32) -> bf16, vectorized
// ---------------------------------------------------------------------------
__global__ __launch_bounds__(256) void cvt_bf16(const float* __restrict__ in,
                                                ushort* __restrict__ out, int n4)
{
    for (int i = blockIdx.x * 256 + threadIdx.x; i < n4; i += gridDim.x * 256) {
        const float4 v = reinterpret_cast<const float4*>(in)[i];
        ushort4 o;
        o.x = f2bf(v.x); o.y = f2bf(v.y); o.z = f2bf(v.z); o.w = f2bf(v.w);
        reinterpret_cast<ushort4*>(out)[i] = o;
    }
}

// ---------------------------------------------------------------------------
// Zero the sentinel rows appended to each feature table.
// ---------------------------------------------------------------------------
__global__ __launch_bounds__(128) void zero_rows(ushort* __restrict__ xbz,
                                                 ushort* __restrict__ f1z,
                                                 ushort* __restrict__ f2z)
{
    const int t = threadIdx.x;
    if (t < 96) xbz[t] = 0;
    if (t < 64) { f1z[t] = 0; f2z[t] = 0; }
}

// ---------------------------------------------------------------------------
// Pack W[K][CIN][64] fp32 -> bf16 B-fragments (16x16x32 shape).
// Slice s = (tap*KB + kb)*4 + cb; lane l holds W[kb*32+(l>>4)*8+e][cb*16+(l&15)].
// ---------------------------------------------------------------------------
template<int K, int CIN>
__global__ __launch_bounds__(256) void pack_W(const float* __restrict__ W,
                                              ushort* __restrict__ Bp)
{
    constexpr int KB = CIN / 32;
    const int t = blockIdx.x * 256 + threadIdx.x;
    if (t >= K * KB * 4 * 64) return;
    const int l = t & 63;
    const int s = t >> 6;
    const int cb = s & 3;
    const int kk = s >> 2;
    const int kb = kk % KB;
    const int tap = kk / KB;
    const int k0 = kb * 32 + (l >> 4) * 8;
    const int col = cb * 16 + (l & 15);
    bf16x8 v;
#pragma unroll
    for (int e = 0; e < 8; ++e)
        v[e] = (short)f2bf(W[((size_t)tap * CIN + k0 + e) * 64 + col]);
    *reinterpret_cast<bf16x8*>(Bp + (size_t)t * 8) = v;
}

// ---------------------------------------------------------------------------
// Sparse conv via MFMA 16x16x32 bf16 -- R7 pipeline at HALF block size.
// Block: 128 thr = 2 waves, 32 output rows; wave w: rows w*16..+15 x 64 cols.
// Doubles independent barrier domains per CU (conv1 ~5.8, conv3 ~5.9 blocks/CU
// vs R7's 3.66) and halves barrier population -> better round overlap.
// B double-buffered in LDS (global_load_lds); counted-vmcnt barrier keeps the
// scattered next-tap A-gathers in flight across the barrier (vmcnt(KB):
// per-wave outstanding at barrier = [stage CPW, gather KB], KB newest).
// Sentinel rows -> appended zero row. Grid XCD-swizzled for L2 locality.
// ---------------------------------------------------------------------------
template<int K, int CIN, bool LEAKY, bool OUTF32>
__global__ __launch_bounds__(128) void sconv_dg(
    const ushort* __restrict__ fin,      // [nin+1][CIN], row nin == zeros
    const int* __restrict__ nmap,        // [nout][K]
    const ushort* __restrict__ Bp,       // packed B fragments
    const float* __restrict__ bias,      // [64]
    void* __restrict__ fout, int nout)
{
    constexpr int KB = CIN / 32;       // 32-k blocks per tap (A frags per lane)
    constexpr int CHUNKS = KB * 4;     // 1KB fragment-chunks per tap slice
    constexpr int CPW = CHUNKS / 2;    // chunks staged per wave (2 waves)
    __shared__ int idxc[32 * K];
    __shared__ ushort Bbuf[2][CHUNKS * 512];

    const int tid = threadIdx.x;
    const int l = tid & 63;
    const int w = tid >> 6;            // 0..1
    const int base = xcd_swizzle(blockIdx.x, gridDim.x) * 32;

    // cache this block's nmap rows (coalesced); OOB rows use row 0 (discarded)
    for (int e = tid; e < 32 * K; e += 128) {
        const int r = base + e / K;
        idxc[e] = (r < nout) ? nmap[(size_t)r * K + (e % K)] : 0;
    }
    __syncthreads();

    const int lrow = l & 15;
    const int grp = l >> 4;
    const int myrow = w * 16 + lrow;
    const int koff = grp * 8;          // ushort offset inside a 32-k chunk

    f32x4 acc[4];
#pragma unroll
    for (int cb = 0; cb < 4; ++cb) acc[cb] = (f32x4){0.f, 0.f, 0.f, 0.f};

    // ---- helpers (macros keep all indexing compile-time static) ----
#define STAGE_B(tap, buf)                                                    \
    {                                                                        \
        _Pragma("unroll")                                                    \
        for (int j = 0; j < CPW; ++j) {                                      \
            const int c = w * CPW + j;                                       \
            gload_lds16(Bp + (size_t)(tap) * CHUNKS * 512 + c * 512 + l * 8, \
                        &Bbuf[buf][c * 512]);                                \
        }                                                                    \
    }

#define GATHER_A(SET, tap)                                                   \
    {                                                                        \
        const size_t idx_ = (size_t)idxc[myrow * K + (tap)];                 \
        const ushort* rp_ = fin + idx_ * CIN + koff;                         \
        _Pragma("unroll")                                                    \
        for (int kb = 0; kb < KB; ++kb)                                      \
            SET[kb] = *reinterpret_cast<const bf16x8*>(rp_ + kb * 32);       \
    }

#define COMPUTE(SET, buf)                                                    \
    {                                                                        \
        _Pragma("unroll")                                                    \
        for (int kb = 0; kb < KB; ++kb) {                                    \
            _Pragma("unroll")                                                \
            for (int cb = 0; cb < 4; ++cb) {                                 \
                const bf16x8 b_ = *reinterpret_cast<const bf16x8*>(          \
                    &Bbuf[buf][(kb * 4 + cb) * 512 + l * 8]);                \
                acc[cb] = __builtin_amdgcn_mfma_f32_16x16x32_bf16(           \
                    SET[kb], b_, acc[cb], 0, 0, 0);                          \
            }                                                                \
        }                                                                    \
    }

    // counted-vmcnt barrier: drain own B-stage, keep A-gathers in flight
#define PIPE_BARRIER()                                                       \
    {                                                                        \
        __builtin_amdgcn_sched_barrier(0);                                   \
        asm volatile("s_waitcnt vmcnt(%0)" :: "n"(KB) : "memory");           \
        __builtin_amdgcn_s_barrier();                                        \
        __builtin_amdgcn_sched_barrier(0);                                   \
    }

    bf16x8 aA[KB], aB[KB];
    STAGE_B(0, 0);
    GATHER_A(aA, 0);
    PIPE_BARRIER();    // buf0 staged; A(0) in flight

    for (int kp = 0; kp < K; kp += 2) {
        // round kp: stage kp+1 into buf1 + gather A(kp+1), compute tap kp
        if (kp + 1 < K) { STAGE_B(kp + 1, 1); GATHER_A(aB, kp + 1); }
        COMPUTE(aA, 0);
        if (kp + 1 < K) {
            PIPE_BARRIER();
            // round kp+1: stage kp+2 into buf0 + gather A(kp+2), compute kp+1
            if (kp + 2 < K) { STAGE_B(kp + 2, 0); GATHER_A(aA, kp + 2); }
            COMPUTE(aB, 1);
            if (kp + 2 < K) PIPE_BARRIER();
        }
    }
#undef STAGE_B
#undef GATHER_A
#undef COMPUTE
#undef PIPE_BARRIER

    // ---- epilogue: D row = grp*4+i, col = cb*16+lrow (m89-verified) ----
    const int r0 = base + w * 16 + grp * 4;
#pragma unroll
    for (int cb = 0; cb < 4; ++cb) {
        const int col = cb * 16 + lrow;
        const float bcol = bias[col];
#pragma unroll
        for (int i = 0; i < 4; ++i) {
            const int r = r0 + i;
            if (r < nout) {
                float o = acc[cb][i] + bcol;
                if (LEAKY) o = o >= 0.f ? o : LRELU_SLOPE * o;
                if (OUTF32) reinterpret_cast<float*>(fout)[(size_t)r * 64 + col] = o;
                else        reinterpret_cast<ushort*>(fout)[(size_t)r * 64 + col] = f2bf(o);
            }
        }
    }
}

// ---------------------------------------------------------------------------
// BatchNorm stage 1 (bf16 input): deterministic per-block partial sum/sumsq.
// ---------------------------------------------------------------------------
__global__ __launch_bounds__(256) void bn_partial(const ushort* __restrict__ f2v, int n2,
                                                  float* __restrict__ partials)
{
    const int c = threadIdx.x & 63;
    const int g = threadIdx.x >> 6;
    float s = 0.f, ss = 0.f;
    for (int r = blockIdx.x * 4 + g; r < n2; r += gridDim.x * 4) {
        const float v = bf2f(f2v[(size_t)r * 64 + c]);
        s += v;
        ss = fmaf(v, v, ss);
    }
    __shared__ float red[4][128];
    red[g][c] = s;
    red[g][64 + c] = ss;
    __syncthreads();
    if (g == 0) {
        partials[(size_t)blockIdx.x * 128 + c] =
            red[0][c] + red[1][c] + red[2][c] + red[3][c];
        partials[(size_t)blockIdx.x * 128 + 64 + c] =
            red[0][64 + c] + red[1][64 + c] + red[2][64 + c] + red[3][64 + c];
    }
}

// ---------------------------------------------------------------------------
// BatchNorm stage 2: PARALLEL final reduce (1024 thr = 8 row-groups x 128 cols)
// -> per-channel affine a,b with scale folded.
// ---------------------------------------------------------------------------
__global__ __launch_bounds__(1024) void bn_finalize(const float* __restrict__ partials, int n2,
                                                    const float* __restrict__ gamma,
                                                    const float* __restrict__ beta,
                                                    const float* __restrict__ scale,
                                                    float* __restrict__ affA, float* __restrict__ affB)
{
    const int t = threadIdx.x;
    const int col = t & 127;
    const int g = t >> 7;
    float s = 0.f;
#pragma unroll
    for (int b = g; b < BN_NB; b += 8)
        s += partials[(size_t)b * 128 + col];
    __shared__ float red[8][128];
    red[g][col] = s;
    __syncthreads();
    if (g == 0) {
        float S = red[0][col];
#pragma unroll
        for (int i = 1; i < 8; ++i) S += red[i][col];
        red[0][col] = S;
    }
    __syncthreads();
    if (t < 64) {
        const float S = red[0][t];
        const float SS = red[0][64 + t];
        const float inv_n = 1.f / (float)n2;
        const float mu = S * inv_n;
        const float var = fmaxf(SS * inv_n - mu * mu, 0.f);
        const float rs = rsqrtf(var + 1e-5f);
        const float sc = scale[0];
        const float ga = gamma[t];
        affA[t] = rs * ga * sc;
        affB[t] = (beta[t] - mu * rs * ga) * sc;
    }
}

// ---------------------------------------------------------------------------
// In-place BN affine on f2 (bf16): f2 = f2*a + b. Elementwise, deterministic.
// ---------------------------------------------------------------------------
__global__ __launch_bounds__(256) void aff_apply(ushort* __restrict__ f2, int nchunk,
                                                 const float* __restrict__ affA,
                                                 const float* __restrict__ affB)
{
    for (int i = blockIdx.x * 256 + threadIdx.x; i < nchunk; i += gridDim.x * 256) {
        const int c = i & 7;  // chunk-within-row
        bf16x8 v = *reinterpret_cast<const bf16x8*>(f2 + (size_t)i * 8);
#pragma unroll
        for (int j = 0; j < 8; ++j)
            v[j] = (short)f2bf(fmaf(bf2f((ushort)v[j]), affA[c * 8 + j], affB[c * 8 + j]));
        *reinterpret_cast<bf16x8*>(f2 + (size_t)i * 8) = v;
    }
}

extern "C" void kernel_launch(void* const* d_in, const int* in_sizes, int n_in,
                              void* d_out, int out_size, void* d_ws, size_t ws_size,
                              hipStream_t stream)
{
    const float* x     = (const float*)d_in[0];
    const float* W1    = (const float*)d_in[1];
    const float* b1    = (const float*)d_in[2];
    const float* W2    = (const float*)d_in[3];
    const float* b2    = (const float*)d_in[4];
    const float* W3    = (const float*)d_in[5];
    const float* b3    = (const float*)d_in[6];
    const float* gamma = (const float*)d_in[7];
    const float* beta  = (const float*)d_in[8];
    const float* scale = (const float*)d_in[9];
    const int* nmap1   = (const int*)d_in[10];
    const int* nmap2   = (const int*)d_in[11];
    const int* nmap3   = (const int*)d_in[12];

    const int N  = in_sizes[0] / 96;    // stride-1 points
    const int N2 = in_sizes[11] / 8;    // stride-2 points

    // workspace (all regions 16B-aligned; +1 zero row per feature table)
    ushort* xb  = (ushort*)d_ws;                    // [N+1,96] bf16
    ushort* f1  = xb + (size_t)(N + 1) * 96;        // [N+1,64] bf16
    ushort* f2  = f1 + (size_t)(N + 1) * 64;        // [N2+1,64] bf16
    ushort* Bp1 = f2 + (size_t)(N2 + 1) * 64;       // 27*96*64 bf16
    ushort* Bp2 = Bp1 + 27 * 96 * 64;               // 8*64*64
    ushort* Bp3 = Bp2 + 8 * 64 * 64;                // 27*64*64
    float* partials = (float*)(Bp3 + 27 * 64 * 64); // [BN_NB,128]
    float* affA = partials + (size_t)BN_NB * 128;   // [64]
    float* affB = affA + 64;                        // [64]
    float* out  = (float*)d_out;                    // [N2,64] fp32

    // sentinel zero rows + input conversion + weight packing
    zero_rows<<<1, 128, 0, stream>>>(xb + (size_t)N * 96, f1 + (size_t)N * 64,
                                     f2 + (size_t)N2 * 64);
    cvt_bf16<<<2048, 256, 0, stream>>>(x, xb, N * 96 / 4);
    pack_W<27, 96><<<(27 * 3 * 4 * 64 + 255) / 256, 256, 0, stream>>>(W1, Bp1);
    pack_W<8, 64><<<(8 * 2 * 4 * 64 + 255) / 256, 256, 0, stream>>>(W2, Bp2);
    pack_W<27, 64><<<(27 * 2 * 4 * 64 + 255) / 256, 256, 0, stream>>>(W3, Bp3);

    // conv1: k=27, 96->64, leaky
    sconv_dg<27, 96, true, false><<<(N + 31) / 32, 128, 0, stream>>>(
        xb, nmap1, Bp1, b1, f1, N);
    // conv2: k=8, 64->64, leaky (downsample)
    sconv_dg<8, 64, true, false><<<(N2 + 31) / 32, 128, 0, stream>>>(
        f1, nmap2, Bp2, b2, f2, N2);
    // batchnorm stats (two-stage, deterministic) + in-place affine
    bn_partial<<<BN_NB, 256, 0, stream>>>(f2, N2, partials);
    bn_finalize<<<1, 1024, 0, stream>>>(partials, N2, gamma, beta, scale, affA, affB);
    aff_apply<<<2048, 256, 0, stream>>>(f2, N2 * 8, affA, affB);
    // conv3: k=27, 64->64, fp32 out
    sconv_dg<27, 64, false, true><<<(N2 + 31) / 32, 128, 0, stream>>>(
        f2, nmap3, Bp3, b3, out, N2);
}